// Round 2
// baseline (695.996 us; speedup 1.0000x reference)
//
#include <hip/hip_runtime.h>
#include <stdint.h>

#define NN 8192      // nodes
#define WPR 256      // u32 words per bitmask row (8192 bits)

// ---------------------------------------------------------------------------
// Adjacency bitmask build: set semantics (duplicate edges collapse) via atomicOr
// ---------------------------------------------------------------------------
__global__ __launch_bounds__(256) void build_adj(const int* __restrict__ ei,
                                                 uint32_t* __restrict__ mask,
                                                 int E) {
  int t = blockIdx.x * blockDim.x + threadIdx.x;
  if (t >= E) return;
  int a = ei[t];        // e0
  int b = ei[E + t];    // e1
  atomicOr(&mask[(size_t)a * WPR + (b >> 5)], 1u << (b & 31));
  atomicOr(&mask[(size_t)b * WPR + (a >> 5)], 1u << (a & 31));
}

// deg[i] = popcount(mask row i) + 1 (the +I eye). Note: a self-edge bit stays in
// the mask AND the eye adds 1 -> diagonal value 2, matching adj.at[].set + eye.
__global__ __launch_bounds__(256) void degrees(const uint32_t* __restrict__ mask,
                                               float* __restrict__ dinv) {
  int gid = blockIdx.x * blockDim.x + threadIdx.x;
  int row = gid >> 6, lane = gid & 63;
  if (row >= NN) return;
  const uint32_t* r = mask + (size_t)row * WPR;
  int c = 0;
#pragma unroll
  for (int w = 0; w < WPR; w += 64) c += __popc(r[w + lane]);
#pragma unroll
  for (int o = 32; o; o >>= 1) c += __shfl_down(c, o);
  if (lane == 0) dinv[row] = rsqrtf((float)(c + 1));
}

// ---------------------------------------------------------------------------
// fp32 tiled GEMM: C[M,N] = A[M,K] @ B[K,N].  BM=BN=64, BK=32, 256 thr, 4x4 micro
// ---------------------------------------------------------------------------
__global__ __launch_bounds__(256) void gemm_f32(const float* __restrict__ A,
                                                const float* __restrict__ B,
                                                float* __restrict__ C,
                                                int M, int N, int K) {
  __shared__ float As[64][36];  // [m][k], padded: float4-aligned, 2-way max conflict
  __shared__ float Bs[32][64];  // [k][n]
  const int t = threadIdx.x;
  const int tx = t & 15, ty = t >> 4;
  const int m0 = blockIdx.y * 64, n0 = blockIdx.x * 64;
  float acc[4][4] = {};

  for (int k0 = 0; k0 < K; k0 += 32) {
#pragma unroll
    for (int l = 0; l < 2; ++l) {  // A tile 64x32: 2 float4 per thread
      int row = (t >> 3) + l * 32;
      int c4 = (t & 7) * 4;
      float4 v = *(const float4*)&A[(size_t)(m0 + row) * K + k0 + c4];
      *(float4*)&As[row][c4] = v;
    }
#pragma unroll
    for (int l = 0; l < 2; ++l) {  // B tile 32x64: 2 float4 per thread
      int row = (t >> 4) + l * 16;
      int c4 = (t & 15) * 4;
      float4 v = *(const float4*)&B[(size_t)(k0 + row) * N + n0 + c4];
      *(float4*)&Bs[row][c4] = v;
    }
    __syncthreads();
#pragma unroll
    for (int k = 0; k < 32; ++k) {
      float a0 = As[ty * 4 + 0][k];
      float a1 = As[ty * 4 + 1][k];
      float a2 = As[ty * 4 + 2][k];
      float a3 = As[ty * 4 + 3][k];
      float4 bv = *(const float4*)&Bs[k][tx * 4];
      acc[0][0] += a0 * bv.x; acc[0][1] += a0 * bv.y; acc[0][2] += a0 * bv.z; acc[0][3] += a0 * bv.w;
      acc[1][0] += a1 * bv.x; acc[1][1] += a1 * bv.y; acc[1][2] += a1 * bv.z; acc[1][3] += a1 * bv.w;
      acc[2][0] += a2 * bv.x; acc[2][1] += a2 * bv.y; acc[2][2] += a2 * bv.z; acc[2][3] += a2 * bv.w;
      acc[3][0] += a3 * bv.x; acc[3][1] += a3 * bv.y; acc[3][2] += a3 * bv.z; acc[3][3] += a3 * bv.w;
    }
    __syncthreads();
  }
#pragma unroll
  for (int i = 0; i < 4; ++i) {
    float4 v = make_float4(acc[i][0], acc[i][1], acc[i][2], acc[i][3]);
    *(float4*)&C[(size_t)(m0 + ty * 4 + i) * N + n0 + tx * 4] = v;
  }
}

// ---------------------------------------------------------------------------
// SpMM: out[row,:] = dinv[row] * ( sum_{j in bits(row)} dinv[j]*Y[j,:]
//                                  + dinv[row]*Y[row,:] )   + bias,  opt. ReLU
// One block (256 thr) per row; bit-scan of the mask row from LDS (wave-uniform).
// ---------------------------------------------------------------------------
template <int NC, bool RELU>
__global__ __launch_bounds__(256) void spmm(const uint32_t* __restrict__ mask,
                                            const float* __restrict__ dinv,
                                            const float* __restrict__ Y,
                                            const float* __restrict__ bias,
                                            float* __restrict__ out) {
  const int row = blockIdx.x, t = threadIdx.x;
  __shared__ uint32_t w[WPR];
  w[t] = mask[(size_t)row * WPR + t];
  __syncthreads();

  float a0 = 0.f, a1 = 0.f;
  for (int wi = 0; wi < WPR; ++wi) {
    uint32_t word = w[wi];
    while (word) {  // uniform across block: all threads read same LDS word
      int j = (wi << 5) + __ffs(word) - 1;
      word &= word - 1;
      float s = dinv[j];
      if constexpr (NC == 512) {
        float2 v = *(const float2*)&Y[(size_t)j * NC + 2 * t];
        a0 += s * v.x;
        a1 += s * v.y;
      } else {
        a0 += s * Y[(size_t)j * NC + t];
      }
    }
  }
  float di = dinv[row];
  if constexpr (NC == 512) {
    float2 v = *(const float2*)&Y[(size_t)row * NC + 2 * t];  // +I self loop
    a0 += di * v.x;
    a1 += di * v.y;
    float o0 = di * a0 + bias[2 * t];
    float o1 = di * a1 + bias[2 * t + 1];
    if (RELU) { o0 = fmaxf(o0, 0.f); o1 = fmaxf(o1, 0.f); }
    *(float2*)&out[(size_t)row * NC + 2 * t] = make_float2(o0, o1);
  } else {
    a0 += di * Y[(size_t)row * NC + t];  // +I self loop
    float o = di * a0 + bias[t];
    if (RELU) o = fmaxf(o, 0.f);
    out[(size_t)row * NC + t] = o;
  }
}

// ---------------------------------------------------------------------------
extern "C" void kernel_launch(void* const* d_in, const int* in_sizes, int n_in,
                              void* d_out, int out_size, void* d_ws, size_t ws_size,
                              hipStream_t stream) {
  const float* x  = (const float*)d_in[0];
  const int*   ei = (const int*)d_in[1];
  const float* W1 = (const float*)d_in[2];
  const float* b1 = (const float*)d_in[3];
  const float* W2 = (const float*)d_in[4];
  const float* b2 = (const float*)d_in[5];
  const float* W3 = (const float*)d_in[6];
  const float* b3 = (const float*)d_in[7];
  float* out = (float*)d_out;
  const int E = in_sizes[1] / 2;

  uint8_t* ws = (uint8_t*)d_ws;
  uint32_t* mask = (uint32_t*)ws;                               // 8 MB
  float* dinv = (float*)(ws + (size_t)8 * 1024 * 1024);         // 32 KB
  float* bufA = (float*)(ws + (size_t)8 * 1024 * 1024 + 64 * 1024);  // 16 MB
  float* bufB = bufA + (size_t)NN * 512;                        // 16 MB

  // ws is poisoned 0xAA before every call -> rebuild adjacency every launch
  hipMemsetAsync(mask, 0, (size_t)NN * WPR * sizeof(uint32_t), stream);
  build_adj<<<(E + 255) / 256, 256, 0, stream>>>(ei, mask, E);
  degrees<<<(NN * 64) / 256, 256, 0, stream>>>(mask, dinv);

  // Layer 1: Y = x@W1 ; H1 = relu(spmm(Y) + b1)
  gemm_f32<<<dim3(512 / 64, NN / 64), 256, 0, stream>>>(x, W1, bufA, NN, 512, 512);
  spmm<512, true><<<NN, 256, 0, stream>>>(mask, dinv, bufA, b1, bufB);

  // Layer 2
  gemm_f32<<<dim3(512 / 64, NN / 64), 256, 0, stream>>>(bufB, W2, bufA, NN, 512, 512);
  spmm<512, true><<<NN, 256, 0, stream>>>(mask, dinv, bufA, b2, bufB);

  // Layer 3 (no ReLU), writes d_out
  gemm_f32<<<dim3(256 / 64, NN / 64), 256, 0, stream>>>(bufB, W3, bufA, NN, 256, 512);
  spmm<256, false><<<NN, 256, 0, stream>>>(mask, dinv, bufA, b3, out);
}

// Round 4
// 543.878 us; speedup vs baseline: 1.2797x; 1.2797x over previous
//
#include <hip/hip_runtime.h>
#include <stdint.h>

#define NN 8192       // nodes
#define WPR 256       // u32 words per bitmask row (8192 bits)
#define CSTRIDE 192   // CSR slots/row; P[deg>192] ~ 1e-40 for Poisson(64); writes guarded

// ---------------------------------------------------------------------------
// Adjacency bitmask: set semantics (duplicates collapse) via atomicOr
// ---------------------------------------------------------------------------
__global__ __launch_bounds__(256) void build_adj(const int* __restrict__ ei,
                                                 uint32_t* __restrict__ mask,
                                                 int E) {
  int t = blockIdx.x * blockDim.x + threadIdx.x;
  if (t >= E) return;
  int a = ei[t];        // e0
  int b = ei[E + t];    // e1
  atomicOr(&mask[(size_t)a * WPR + (b >> 5)], 1u << (b & 31));
  atomicOr(&mask[(size_t)b * WPR + (a >> 5)], 1u << (a & 31));
}

// ---------------------------------------------------------------------------
// Bitmask -> fixed-stride CSR + dinv. One wave per row: uint4 coalesced mask
// read, wave inclusive-scan for write offsets. Self-edge bit stays (diag=2
// case); eye handled separately in spmm. dinv = rsqrt(popcount+1).
// ---------------------------------------------------------------------------
__global__ __launch_bounds__(256) void mask_to_csr(const uint32_t* __restrict__ mask,
                                                   int* __restrict__ cols,
                                                   int* __restrict__ nnz,
                                                   float* __restrict__ dinv) {
  const int row = blockIdx.x * 4 + (threadIdx.x >> 6);
  const int lane = threadIdx.x & 63;
  const uint4 w = ((const uint4*)(mask + (size_t)row * WPR))[lane];
  const int c = __popc(w.x) + __popc(w.y) + __popc(w.z) + __popc(w.w);
  int inc = c;
#pragma unroll
  for (int o = 1; o < 64; o <<= 1) {
    int v = __shfl_up(inc, o);
    if (lane >= o) inc += v;
  }
  const int total = __shfl(inc, 63);
  int base = row * CSTRIDE + (inc - c);
  const int lim = row * CSTRIDE + CSTRIDE;
  uint32_t ws_[4] = {w.x, w.y, w.z, w.w};
#pragma unroll
  for (int i = 0; i < 4; ++i) {
    uint32_t word = ws_[i];
    int boff = (lane * 4 + i) << 5;
    while (word) {
      int b = __ffs(word) - 1;
      word &= word - 1;
      if (base < lim) cols[base] = boff + b;
      ++base;
    }
  }
  if (lane == 0) {
    nnz[row] = (total > CSTRIDE) ? CSTRIDE : total;
    dinv[row] = rsqrtf((float)(total + 1));
  }
}

// ---------------------------------------------------------------------------
// fp32 tiled GEMM with row-scaled epilogue: C[m,:] = rs[m] * (A@B)[m,:]
// BM=BN=64, BK=32, 256 thr, 4x4 micro
// ---------------------------------------------------------------------------
__global__ __launch_bounds__(256) void gemm_f32s(const float* __restrict__ A,
                                                 const float* __restrict__ B,
                                                 const float* __restrict__ rs,
                                                 float* __restrict__ C,
                                                 int M, int N, int K) {
  __shared__ float As[64][36];
  __shared__ float Bs[32][64];
  const int t = threadIdx.x;
  const int tx = t & 15, ty = t >> 4;
  const int m0 = blockIdx.y * 64, n0 = blockIdx.x * 64;
  float acc[4][4] = {};

  for (int k0 = 0; k0 < K; k0 += 32) {
#pragma unroll
    for (int l = 0; l < 2; ++l) {
      int row = (t >> 3) + l * 32;
      int c4 = (t & 7) * 4;
      float4 v = *(const float4*)&A[(size_t)(m0 + row) * K + k0 + c4];
      *(float4*)&As[row][c4] = v;
    }
#pragma unroll
    for (int l = 0; l < 2; ++l) {
      int row = (t >> 4) + l * 16;
      int c4 = (t & 15) * 4;
      float4 v = *(const float4*)&B[(size_t)(k0 + row) * N + n0 + c4];
      *(float4*)&Bs[row][c4] = v;
    }
    __syncthreads();
#pragma unroll
    for (int k = 0; k < 32; ++k) {
      float a0 = As[ty * 4 + 0][k];
      float a1 = As[ty * 4 + 1][k];
      float a2 = As[ty * 4 + 2][k];
      float a3 = As[ty * 4 + 3][k];
      float4 bv = *(const float4*)&Bs[k][tx * 4];
      acc[0][0] += a0 * bv.x; acc[0][1] += a0 * bv.y; acc[0][2] += a0 * bv.z; acc[0][3] += a0 * bv.w;
      acc[1][0] += a1 * bv.x; acc[1][1] += a1 * bv.y; acc[1][2] += a1 * bv.z; acc[1][3] += a1 * bv.w;
      acc[2][0] += a2 * bv.x; acc[2][1] += a2 * bv.y; acc[2][2] += a2 * bv.z; acc[2][3] += a2 * bv.w;
      acc[3][0] += a3 * bv.x; acc[3][1] += a3 * bv.y; acc[3][2] += a3 * bv.z; acc[3][3] += a3 * bv.w;
    }
    __syncthreads();
  }
#pragma unroll
  for (int i = 0; i < 4; ++i) {
    float s = rs[m0 + ty * 4 + i];
    float4 v = make_float4(s * acc[i][0], s * acc[i][1], s * acc[i][2], s * acc[i][3]);
    *(float4*)&C[(size_t)(m0 + ty * 4 + i) * N + n0 + tx * 4] = v;
  }
}

// ---------------------------------------------------------------------------
// CSR SpMM over pre-scaled Ys (= dinv[j] * (X@W)[j,:]):
//   out[row,:] = dinv[row] * ( sum_{j in csr(row)} Ys[j,:] + Ys[row,:] ) + bias
// Block per row; indices in LDS; 8-deep unrolled independent gathers.
// ---------------------------------------------------------------------------
template <int NC, bool RELU>
__global__ __launch_bounds__(256) void spmm_csr(const int* __restrict__ cols,
                                                const int* __restrict__ nnz,
                                                const float* __restrict__ dinv,
                                                const float* __restrict__ Ys,
                                                const float* __restrict__ bias,
                                                float* __restrict__ out) {
  const int row = blockIdx.x, t = threadIdx.x;
  __shared__ int cidx[CSTRIDE];
  const int n = nnz[row];
  if (t < CSTRIDE && t < n) cidx[t] = cols[row * CSTRIDE + t];
  __syncthreads();

  if constexpr (NC == 512) {
    float a0 = 0.f, a1 = 0.f;
    int k = 0;
    for (; k + 8 <= n; k += 8) {
      float2 v0 = *(const float2*)&Ys[(size_t)cidx[k + 0] * NC + 2 * t];
      float2 v1 = *(const float2*)&Ys[(size_t)cidx[k + 1] * NC + 2 * t];
      float2 v2 = *(const float2*)&Ys[(size_t)cidx[k + 2] * NC + 2 * t];
      float2 v3 = *(const float2*)&Ys[(size_t)cidx[k + 3] * NC + 2 * t];
      float2 v4 = *(const float2*)&Ys[(size_t)cidx[k + 4] * NC + 2 * t];
      float2 v5 = *(const float2*)&Ys[(size_t)cidx[k + 5] * NC + 2 * t];
      float2 v6 = *(const float2*)&Ys[(size_t)cidx[k + 6] * NC + 2 * t];
      float2 v7 = *(const float2*)&Ys[(size_t)cidx[k + 7] * NC + 2 * t];
      a0 += ((v0.x + v1.x) + (v2.x + v3.x)) + ((v4.x + v5.x) + (v6.x + v7.x));
      a1 += ((v0.y + v1.y) + (v2.y + v3.y)) + ((v4.y + v5.y) + (v6.y + v7.y));
    }
    for (; k < n; ++k) {
      float2 v = *(const float2*)&Ys[(size_t)cidx[k] * NC + 2 * t];
      a0 += v.x; a1 += v.y;
    }
    float2 vs = *(const float2*)&Ys[(size_t)row * NC + 2 * t];  // +I (eye)
    a0 += vs.x; a1 += vs.y;
    const float di = dinv[row];
    float o0 = di * a0 + bias[2 * t];
    float o1 = di * a1 + bias[2 * t + 1];
    if (RELU) { o0 = fmaxf(o0, 0.f); o1 = fmaxf(o1, 0.f); }
    *(float2*)&out[(size_t)row * NC + 2 * t] = make_float2(o0, o1);
  } else {  // NC == 256: one col per thread
    float a0 = 0.f;
    int k = 0;
    for (; k + 8 <= n; k += 8) {
      float v0 = Ys[(size_t)cidx[k + 0] * NC + t];
      float v1 = Ys[(size_t)cidx[k + 1] * NC + t];
      float v2 = Ys[(size_t)cidx[k + 2] * NC + t];
      float v3 = Ys[(size_t)cidx[k + 3] * NC + t];
      float v4 = Ys[(size_t)cidx[k + 4] * NC + t];
      float v5 = Ys[(size_t)cidx[k + 5] * NC + t];
      float v6 = Ys[(size_t)cidx[k + 6] * NC + t];
      float v7 = Ys[(size_t)cidx[k + 7] * NC + t];
      a0 += ((v0 + v1) + (v2 + v3)) + ((v4 + v5) + (v6 + v7));
    }
    for (; k < n; ++k) a0 += Ys[(size_t)cidx[k] * NC + t];
    a0 += Ys[(size_t)row * NC + t];  // +I (eye)
    float o = dinv[row] * a0 + bias[t];
    if (RELU) o = fmaxf(o, 0.f);
    out[(size_t)row * NC + t] = o;
  }
}

// ---------------------------------------------------------------------------
extern "C" void kernel_launch(void* const* d_in, const int* in_sizes, int n_in,
                              void* d_out, int out_size, void* d_ws, size_t ws_size,
                              hipStream_t stream) {
  const float* x  = (const float*)d_in[0];
  const int*   ei = (const int*)d_in[1];
  const float* W1 = (const float*)d_in[2];
  const float* b1 = (const float*)d_in[3];
  const float* W2 = (const float*)d_in[4];
  const float* b2 = (const float*)d_in[5];
  const float* W3 = (const float*)d_in[6];
  const float* b3 = (const float*)d_in[7];
  float* out = (float*)d_out;
  const int E = in_sizes[1] / 2;

  // Workspace layout (38.1 MB total; mask aliases bufB — mask is dead before
  // bufB's first write in spmm layer 1):
  uint8_t* ws = (uint8_t*)d_ws;
  int*      cols = (int*)ws;                                   // 6 MB
  int*      nnz  = (int*)(ws + (size_t)CSTRIDE * NN * 4);      // 32 KB
  float*    dinv = (float*)(ws + (size_t)CSTRIDE * NN * 4 + 32 * 1024);  // 32 KB
  float*    bufA = (float*)(ws + (size_t)CSTRIDE * NN * 4 + 64 * 1024);  // 16 MB
  float*    bufB = bufA + (size_t)NN * 512;                    // 16 MB
  uint32_t* mask = (uint32_t*)bufB;                            // 8 MB (alias)

  // ws is poisoned 0xAA before every call -> rebuild adjacency every launch
  hipMemsetAsync(mask, 0, (size_t)NN * WPR * sizeof(uint32_t), stream);
  build_adj<<<(E + 255) / 256, 256, 0, stream>>>(ei, mask, E);
  mask_to_csr<<<NN / 4, 256, 0, stream>>>(mask, cols, nnz, dinv);

  // Layer 1: Ys = dinv ⊙ (x@W1); H1 = relu(dinv ⊙ (A+I)·Ys + b1)
  gemm_f32s<<<dim3(8, 128), 256, 0, stream>>>(x, W1, dinv, bufA, NN, 512, 512);
  spmm_csr<512, true><<<NN, 256, 0, stream>>>(cols, nnz, dinv, bufA, b1, bufB);

  // Layer 2
  gemm_f32s<<<dim3(8, 128), 256, 0, stream>>>(bufB, W2, dinv, bufA, NN, 512, 512);
  spmm_csr<512, true><<<NN, 256, 0, stream>>>(cols, nnz, dinv, bufA, b2, bufB);

  // Layer 3 (no ReLU), writes d_out
  gemm_f32s<<<dim3(4, 128), 256, 0, stream>>>(bufB, W3, dinv, bufA, NN, 256, 512);
  spmm_csr<256, false><<<NN, 256, 0, stream>>>(cols, nnz, dinv, bufA, b3, out);
}

// Round 5
// 283.064 us; speedup vs baseline: 2.4588x; 1.9214x over previous
//
#include <hip/hip_runtime.h>
#include <stdint.h>

#define NN 8192       // nodes
#define WPR 256       // u32 words per bitmask row (8192 bits)
#define CSTRIDE 192   // CSR slots/row; P[deg>192] ~ 1e-40 for Poisson(64); writes guarded

typedef _Float16 f16;
typedef f16 f16x2 __attribute__((ext_vector_type(2)));
typedef f16 f16x4 __attribute__((ext_vector_type(4)));
typedef f16 f16x8 __attribute__((ext_vector_type(8)));
typedef float f32x4 __attribute__((ext_vector_type(4)));

// ---------------------------------------------------------------------------
// Adjacency bitmask: set semantics (duplicates collapse) via atomicOr
// ---------------------------------------------------------------------------
__global__ __launch_bounds__(256) void build_adj(const int* __restrict__ ei,
                                                 uint32_t* __restrict__ mask,
                                                 int E) {
  int t = blockIdx.x * blockDim.x + threadIdx.x;
  if (t >= E) return;
  int a = ei[t];        // e0
  int b = ei[E + t];    // e1
  atomicOr(&mask[(size_t)a * WPR + (b >> 5)], 1u << (b & 31));
  atomicOr(&mask[(size_t)b * WPR + (a >> 5)], 1u << (a & 31));
}

// ---------------------------------------------------------------------------
// Bitmask -> fixed-stride CSR + dinv. One wave per row. Self-edge bit stays
// (diag=2 case); eye handled separately in spmm. dinv = rsqrt(popcount+1).
// ---------------------------------------------------------------------------
__global__ __launch_bounds__(256) void mask_to_csr(const uint32_t* __restrict__ mask,
                                                   int* __restrict__ cols,
                                                   int* __restrict__ nnz,
                                                   float* __restrict__ dinv) {
  const int row = blockIdx.x * 4 + (threadIdx.x >> 6);
  const int lane = threadIdx.x & 63;
  const uint4 w = ((const uint4*)(mask + (size_t)row * WPR))[lane];
  const int c = __popc(w.x) + __popc(w.y) + __popc(w.z) + __popc(w.w);
  int inc = c;
#pragma unroll
  for (int o = 1; o < 64; o <<= 1) {
    int v = __shfl_up(inc, o);
    if (lane >= o) inc += v;
  }
  const int total = __shfl(inc, 63);
  int base = row * CSTRIDE + (inc - c);
  const int lim = row * CSTRIDE + CSTRIDE;
  uint32_t ws_[4] = {w.x, w.y, w.z, w.w};
#pragma unroll
  for (int i = 0; i < 4; ++i) {
    uint32_t word = ws_[i];
    int boff = (lane * 4 + i) << 5;
    while (word) {
      int b = __ffs(word) - 1;
      word &= word - 1;
      if (base < lim) cols[base] = boff + b;
      ++base;
    }
  }
  if (lane == 0) {
    nnz[row] = (total > CSTRIDE) ? CSTRIDE : total;
    dinv[row] = rsqrtf((float)(total + 1));
  }
}

// ---------------------------------------------------------------------------
// f16-MFMA GEMM: Ys[m,:] = (f16)( rs[m] * (A@W)[m,:] )
// A fp32 [M,K] row-major, W fp32 [K,N] row-major (transposed into LDS n-major).
// BM=128, BN=64, BK=32; 256 thr = 4 waves in 2x2 wave grid; 16x16x32 f16 MFMA.
// A frag: row=lane&15, k=(lane>>4)*8+j. B frag: col=lane&15, same k.
// D frag: row=(lane>>4)*4+r, col=lane&15 (m89-verified, dtype-independent).
// ---------------------------------------------------------------------------
__global__ __launch_bounds__(256) void gemm_f16(const float* __restrict__ A,
                                                const float* __restrict__ W,
                                                const float* __restrict__ rs,
                                                f16* __restrict__ Ys,
                                                int M, int N, int K) {
  __shared__ f16 As[128][40];  // [m][k], pad->2-way conflicts only (free)
  __shared__ f16 Bs[64][40];   // [n][k] (transposed in staging)
  const int t = threadIdx.x;
  const int lane = t & 63;
  const int w = t >> 6;
  const int wr = w >> 1, wc = w & 1;          // 2x2 wave grid
  const int m0 = blockIdx.y * 128, n0 = blockIdx.x * 64;
  const int lm = lane & 15, kg = lane >> 4;   // fragment row/col, k-group
  const int k0f = kg * 8;

  f32x4 acc[4][2] = {};

  for (int k0 = 0; k0 < K; k0 += 32) {
    // stage A: 128x32 fp32 -> f16. 4 float4 per thread.
#pragma unroll
    for (int l = 0; l < 4; ++l) {
      int row = (t >> 3) + l * 32;
      int c4 = (t & 7) * 4;
      float4 v = *(const float4*)&A[(size_t)(m0 + row) * K + k0 + c4];
      f16x4 h = {(f16)v.x, (f16)v.y, (f16)v.z, (f16)v.w};
      *(f16x4*)&As[row][c4] = h;
    }
    // stage W transposed: 32x64 fp32 -> Bs[n][k] f16. 2 float4 per thread.
#pragma unroll
    for (int l = 0; l < 2; ++l) {
      int kr = (t >> 4) + l * 16;
      int nc4 = (t & 15) * 4;
      float4 v = *(const float4*)&W[(size_t)(k0 + kr) * N + n0 + nc4];
      Bs[nc4 + 0][kr] = (f16)v.x;
      Bs[nc4 + 1][kr] = (f16)v.y;
      Bs[nc4 + 2][kr] = (f16)v.z;
      Bs[nc4 + 3][kr] = (f16)v.w;
    }
    __syncthreads();

    f16x8 af[4], bf[2];
#pragma unroll
    for (int mf = 0; mf < 4; ++mf)
      af[mf] = *(const f16x8*)&As[wr * 64 + mf * 16 + lm][k0f];
#pragma unroll
    for (int nf = 0; nf < 2; ++nf)
      bf[nf] = *(const f16x8*)&Bs[wc * 32 + nf * 16 + lm][k0f];
#pragma unroll
    for (int mf = 0; mf < 4; ++mf)
#pragma unroll
      for (int nf = 0; nf < 2; ++nf)
        acc[mf][nf] = __builtin_amdgcn_mfma_f32_16x16x32_f16(af[mf], bf[nf], acc[mf][nf], 0, 0, 0);
    __syncthreads();
  }

  // epilogue: row-scale by rs, convert f16, store
#pragma unroll
  for (int mf = 0; mf < 4; ++mf) {
#pragma unroll
    for (int r = 0; r < 4; ++r) {
      int row = m0 + wr * 64 + mf * 16 + kg * 4 + r;
      float s = rs[row];
#pragma unroll
      for (int nf = 0; nf < 2; ++nf) {
        int col = n0 + wc * 32 + nf * 16 + lm;
        Ys[(size_t)row * N + col] = (f16)(s * acc[mf][nf][r]);
      }
    }
  }
}

// ---------------------------------------------------------------------------
// CSR SpMM over pre-scaled f16 Ys (= dinv[j] * (A@W)[j,:]):
//   out[row,:] = dinv[row] * ( sum_{j in csr(row)} Ys[j,:] + Ys[row,:] ) + bias
// Block per row; indices in LDS; 8-deep unrolled independent gathers; fp32 accum.
// ---------------------------------------------------------------------------
template <int NC, bool RELU>
__global__ __launch_bounds__(256) void spmm_csr(const int* __restrict__ cols,
                                                const int* __restrict__ nnz,
                                                const float* __restrict__ dinv,
                                                const f16* __restrict__ Ys,
                                                const float* __restrict__ bias,
                                                float* __restrict__ out) {
  const int row = blockIdx.x, t = threadIdx.x;
  __shared__ int cidx[CSTRIDE];
  const int n = nnz[row];
  if (t < CSTRIDE && t < n) cidx[t] = cols[row * CSTRIDE + t];
  __syncthreads();

  if constexpr (NC == 512) {
    float a0 = 0.f, a1 = 0.f;
    int k = 0;
    for (; k + 8 <= n; k += 8) {
      f16x2 v0 = *(const f16x2*)&Ys[(size_t)cidx[k + 0] * NC + 2 * t];
      f16x2 v1 = *(const f16x2*)&Ys[(size_t)cidx[k + 1] * NC + 2 * t];
      f16x2 v2 = *(const f16x2*)&Ys[(size_t)cidx[k + 2] * NC + 2 * t];
      f16x2 v3 = *(const f16x2*)&Ys[(size_t)cidx[k + 3] * NC + 2 * t];
      f16x2 v4 = *(const f16x2*)&Ys[(size_t)cidx[k + 4] * NC + 2 * t];
      f16x2 v5 = *(const f16x2*)&Ys[(size_t)cidx[k + 5] * NC + 2 * t];
      f16x2 v6 = *(const f16x2*)&Ys[(size_t)cidx[k + 6] * NC + 2 * t];
      f16x2 v7 = *(const f16x2*)&Ys[(size_t)cidx[k + 7] * NC + 2 * t];
      a0 += (((float)v0[0] + (float)v1[0]) + ((float)v2[0] + (float)v3[0])) +
            (((float)v4[0] + (float)v5[0]) + ((float)v6[0] + (float)v7[0]));
      a1 += (((float)v0[1] + (float)v1[1]) + ((float)v2[1] + (float)v3[1])) +
            (((float)v4[1] + (float)v5[1]) + ((float)v6[1] + (float)v7[1]));
    }
    for (; k < n; ++k) {
      f16x2 v = *(const f16x2*)&Ys[(size_t)cidx[k] * NC + 2 * t];
      a0 += (float)v[0]; a1 += (float)v[1];
    }
    f16x2 vs = *(const f16x2*)&Ys[(size_t)row * NC + 2 * t];  // +I (eye)
    a0 += (float)vs[0]; a1 += (float)vs[1];
    const float di = dinv[row];
    float o0 = di * a0 + bias[2 * t];
    float o1 = di * a1 + bias[2 * t + 1];
    if (RELU) { o0 = fmaxf(o0, 0.f); o1 = fmaxf(o1, 0.f); }
    *(float2*)&out[(size_t)row * NC + 2 * t] = make_float2(o0, o1);
  } else {  // NC == 256: one col per thread
    float a0 = 0.f;
    int k = 0;
    for (; k + 8 <= n; k += 8) {
      float v0 = (float)Ys[(size_t)cidx[k + 0] * NC + t];
      float v1 = (float)Ys[(size_t)cidx[k + 1] * NC + t];
      float v2 = (float)Ys[(size_t)cidx[k + 2] * NC + t];
      float v3 = (float)Ys[(size_t)cidx[k + 3] * NC + t];
      float v4 = (float)Ys[(size_t)cidx[k + 4] * NC + t];
      float v5 = (float)Ys[(size_t)cidx[k + 5] * NC + t];
      float v6 = (float)Ys[(size_t)cidx[k + 6] * NC + t];
      float v7 = (float)Ys[(size_t)cidx[k + 7] * NC + t];
      a0 += ((v0 + v1) + (v2 + v3)) + ((v4 + v5) + (v6 + v7));
    }
    for (; k < n; ++k) a0 += (float)Ys[(size_t)cidx[k] * NC + t];
    a0 += (float)Ys[(size_t)row * NC + t];  // +I (eye)
    float o = dinv[row] * a0 + bias[t];
    if (RELU) o = fmaxf(o, 0.f);
    out[(size_t)row * NC + t] = o;
  }
}

// ---------------------------------------------------------------------------
extern "C" void kernel_launch(void* const* d_in, const int* in_sizes, int n_in,
                              void* d_out, int out_size, void* d_ws, size_t ws_size,
                              hipStream_t stream) {
  const float* x  = (const float*)d_in[0];
  const int*   ei = (const int*)d_in[1];
  const float* W1 = (const float*)d_in[2];
  const float* b1 = (const float*)d_in[3];
  const float* W2 = (const float*)d_in[4];
  const float* b2 = (const float*)d_in[5];
  const float* W3 = (const float*)d_in[6];
  const float* b3 = (const float*)d_in[7];
  float* out = (float*)d_out;
  const int E = in_sizes[1] / 2;

  // Workspace (~30 MB). mask aliases Ys: mask dead after mask_to_csr, before
  // the first gemm_f16 write to Ys.
  uint8_t* ws = (uint8_t*)d_ws;
  int*      cols = (int*)ws;                                              // 6 MB
  int*      nnz  = (int*)(ws + (size_t)CSTRIDE * NN * 4);                 // 32 KB
  float*    dinv = (float*)(ws + (size_t)CSTRIDE * NN * 4 + 32 * 1024);   // 32 KB
  float*    bufH = (float*)(ws + (size_t)CSTRIDE * NN * 4 + 64 * 1024);   // 16 MB fp32 H
  f16*      Ys   = (f16*)(bufH + (size_t)NN * 512);                       // 8 MB f16
  uint32_t* mask = (uint32_t*)Ys;                                         // 8 MB (alias)

  // ws is poisoned 0xAA before every call -> rebuild adjacency every launch
  hipMemsetAsync(mask, 0, (size_t)NN * WPR * sizeof(uint32_t), stream);
  build_adj<<<(E + 255) / 256, 256, 0, stream>>>(ei, mask, E);
  mask_to_csr<<<NN / 4, 256, 0, stream>>>(mask, cols, nnz, dinv);

  // Layer 1: Ys = f16(dinv ⊙ (x@W1)); H1 = relu(dinv ⊙ ((A+I)·Ys) + b1)
  gemm_f16<<<dim3(8, 64), 256, 0, stream>>>(x, W1, dinv, Ys, NN, 512, 512);
  spmm_csr<512, true><<<NN, 256, 0, stream>>>(cols, nnz, dinv, Ys, b1, bufH);

  // Layer 2
  gemm_f16<<<dim3(8, 64), 256, 0, stream>>>(bufH, W2, dinv, Ys, NN, 512, 512);
  spmm_csr<512, true><<<NN, 256, 0, stream>>>(cols, nnz, dinv, Ys, b2, bufH);

  // Layer 3 (no ReLU), writes d_out
  gemm_f16<<<dim3(4, 64), 256, 0, stream>>>(bufH, W3, dinv, Ys, NN, 256, 512);
  spmm_csr<256, false><<<NN, 256, 0, stream>>>(cols, nnz, dinv, Ys, b3, out);
}

// Round 6
// 240.165 us; speedup vs baseline: 2.8980x; 1.1786x over previous
//
#include <hip/hip_runtime.h>
#include <stdint.h>

#define NN 8192       // nodes
#define WPR 256       // u32 words per bitmask row (8192 bits)
#define CSTRIDE 192   // CSR slots/row; P[deg>192] ~ 1e-40 for Poisson(64); writes guarded

typedef _Float16 f16;
typedef f16 f16x2 __attribute__((ext_vector_type(2)));
typedef f16 f16x4 __attribute__((ext_vector_type(4)));
typedef f16 f16x8 __attribute__((ext_vector_type(8)));
typedef float f32x4 __attribute__((ext_vector_type(4)));

// ---------------------------------------------------------------------------
// Adjacency bitmask: set semantics (duplicates collapse) via atomicOr
// ---------------------------------------------------------------------------
__global__ __launch_bounds__(256) void build_adj(const int* __restrict__ ei,
                                                 uint32_t* __restrict__ mask,
                                                 int E) {
  int t = blockIdx.x * blockDim.x + threadIdx.x;
  if (t >= E) return;
  int a = ei[t];        // e0
  int b = ei[E + t];    // e1
  atomicOr(&mask[(size_t)a * WPR + (b >> 5)], 1u << (b & 31));
  atomicOr(&mask[(size_t)b * WPR + (a >> 5)], 1u << (a & 31));
}

// ---------------------------------------------------------------------------
// Bitmask -> fixed-stride CSR (uint16 ids) + dinv. One wave per row. Self-edge
// bit stays (diag=2 case); eye handled separately in spmm. dinv=rsqrt(pop+1).
// ---------------------------------------------------------------------------
__global__ __launch_bounds__(256) void mask_to_csr(const uint32_t* __restrict__ mask,
                                                   uint16_t* __restrict__ cols,
                                                   int* __restrict__ nnz,
                                                   float* __restrict__ dinv) {
  const int row = blockIdx.x * 4 + (threadIdx.x >> 6);
  const int lane = threadIdx.x & 63;
  const uint4 w = ((const uint4*)(mask + (size_t)row * WPR))[lane];
  const int c = __popc(w.x) + __popc(w.y) + __popc(w.z) + __popc(w.w);
  int inc = c;
#pragma unroll
  for (int o = 1; o < 64; o <<= 1) {
    int v = __shfl_up(inc, o);
    if (lane >= o) inc += v;
  }
  const int total = __shfl(inc, 63);
  int base = row * CSTRIDE + (inc - c);
  const int lim = row * CSTRIDE + CSTRIDE;
  uint32_t ws_[4] = {w.x, w.y, w.z, w.w};
#pragma unroll
  for (int i = 0; i < 4; ++i) {
    uint32_t word = ws_[i];
    int boff = (lane * 4 + i) << 5;
    while (word) {
      int b = __ffs(word) - 1;
      word &= word - 1;
      if (base < lim) cols[base] = (uint16_t)(boff + b);
      ++base;
    }
  }
  if (lane == 0) {
    nnz[row] = (total > CSTRIDE) ? CSTRIDE : total;
    dinv[row] = rsqrtf((float)(total + 1));
  }
}

// ---------------------------------------------------------------------------
// f16-MFMA GEMM: Ys[m,:] = (f16)( rs[m] * (A@W)[m,:] )
// A [M,K] row-major (fp32 or f16), W fp32 [K,N] (transposed into LDS n-major).
// BM=128, BN=64, BK=32; 256 thr = 2x2 waves; 16x16x32 f16 MFMA.
// A frag: row=lane&15, k=(lane>>4)*8+j. B frag: col=lane&15, same k.
// D frag: row=(lane>>4)*4+r, col=lane&15 (m89-verified, dtype-independent).
// ---------------------------------------------------------------------------
template <typename AT>
__global__ __launch_bounds__(256) void gemm_f16(const AT* __restrict__ A,
                                                const float* __restrict__ W,
                                                const float* __restrict__ rs,
                                                f16* __restrict__ Ys,
                                                int M, int N, int K) {
  __shared__ f16 As[128][40];  // [m][k], pad->2-way conflicts only (free)
  __shared__ f16 Bs[64][40];   // [n][k] (transposed in staging)
  const int t = threadIdx.x;
  const int lane = t & 63;
  const int w = t >> 6;
  const int wr = w >> 1, wc = w & 1;          // 2x2 wave grid
  const int m0 = blockIdx.y * 128, n0 = blockIdx.x * 64;
  const int lm = lane & 15, kg = lane >> 4;   // fragment row/col, k-group
  const int k0f = kg * 8;

  f32x4 acc[4][2] = {};

  for (int k0 = 0; k0 < K; k0 += 32) {
    if constexpr (sizeof(AT) == 4) {
      // stage A: 128x32 fp32 -> f16. 4 float4 per thread.
#pragma unroll
      for (int l = 0; l < 4; ++l) {
        int row = (t >> 3) + l * 32;
        int c4 = (t & 7) * 4;
        float4 v = *(const float4*)&A[(size_t)(m0 + row) * K + k0 + c4];
        f16x4 h = {(f16)v.x, (f16)v.y, (f16)v.z, (f16)v.w};
        *(f16x4*)&As[row][c4] = h;
      }
    } else {
      // stage A: 128x32 f16 direct. 2 f16x8 per thread.
#pragma unroll
      for (int l = 0; l < 2; ++l) {
        int idx = l * 256 + t;
        int row = idx >> 2;
        int c8 = (idx & 3) * 8;
        f16x8 h = *(const f16x8*)&A[(size_t)(m0 + row) * K + k0 + c8];
        *(f16x8*)&As[row][c8] = h;
      }
    }
    // stage W transposed: 32x64 fp32 -> Bs[n][k] f16. 2 float4 per thread.
#pragma unroll
    for (int l = 0; l < 2; ++l) {
      int kr = (t >> 4) + l * 16;
      int nc4 = (t & 15) * 4;
      float4 v = *(const float4*)&W[(size_t)(k0 + kr) * N + n0 + nc4];
      Bs[nc4 + 0][kr] = (f16)v.x;
      Bs[nc4 + 1][kr] = (f16)v.y;
      Bs[nc4 + 2][kr] = (f16)v.z;
      Bs[nc4 + 3][kr] = (f16)v.w;
    }
    __syncthreads();

    f16x8 af[4], bf[2];
#pragma unroll
    for (int mf = 0; mf < 4; ++mf)
      af[mf] = *(const f16x8*)&As[wr * 64 + mf * 16 + lm][k0f];
#pragma unroll
    for (int nf = 0; nf < 2; ++nf)
      bf[nf] = *(const f16x8*)&Bs[wc * 32 + nf * 16 + lm][k0f];
#pragma unroll
    for (int mf = 0; mf < 4; ++mf)
#pragma unroll
      for (int nf = 0; nf < 2; ++nf)
        acc[mf][nf] = __builtin_amdgcn_mfma_f32_16x16x32_f16(af[mf], bf[nf], acc[mf][nf], 0, 0, 0);
    __syncthreads();
  }

  // epilogue: row-scale by rs, convert f16, store
#pragma unroll
  for (int mf = 0; mf < 4; ++mf) {
#pragma unroll
    for (int r = 0; r < 4; ++r) {
      int row = m0 + wr * 64 + mf * 16 + kg * 4 + r;
      float s = rs[row];
#pragma unroll
      for (int nf = 0; nf < 2; ++nf) {
        int col = n0 + wc * 32 + nf * 16 + lm;
        Ys[(size_t)row * N + col] = (f16)(s * acc[mf][nf][r]);
      }
    }
  }
}

// ---------------------------------------------------------------------------
// Column-chunked CSR SpMM with XCD affinity.
//   out[row, chunk] = dinv[row]*( sum_j Ys[j, chunk] + Ys[row, chunk] ) + bias
// chunk = blockIdx % Q (Q = NC/128): under round-robin block->XCD dispatch,
// each XCD touches ONE 2 MB column chunk of Ys -> L2-resident gathers.
// Block = 4 rows x 1 chunk; one wave per row; lane covers 2 cols (f16x2).
// ---------------------------------------------------------------------------
template <int NC, typename OutT, bool RELU>
__global__ __launch_bounds__(256) void spmm_csr(const uint16_t* __restrict__ cols,
                                                const int* __restrict__ nnz,
                                                const float* __restrict__ dinv,
                                                const f16* __restrict__ Ys,
                                                const float* __restrict__ bias,
                                                OutT* __restrict__ out) {
  constexpr int Q = NC / 128;
  const int b = blockIdx.x;
  const int chunk = b % Q;          // == XCD%Q under round-robin dispatch
  const int rg = b / Q;
  const int w = threadIdx.x >> 6, lane = threadIdx.x & 63;
  const int row = rg * 4 + w;
  const int cb = chunk * 128 + 2 * lane;

  __shared__ uint16_t cidx[4][CSTRIDE];
  const int n = nnz[row];
  for (int k = lane; k < n; k += 64) cidx[w][k] = cols[row * CSTRIDE + k];
  __syncthreads();

  const f16* __restrict__ Yc = Ys + cb;
  float a0 = 0.f, a1 = 0.f;
  int k = 0;
  for (; k + 8 <= n; k += 8) {
    f16x2 v0 = *(const f16x2*)&Yc[(size_t)cidx[w][k + 0] * NC];
    f16x2 v1 = *(const f16x2*)&Yc[(size_t)cidx[w][k + 1] * NC];
    f16x2 v2 = *(const f16x2*)&Yc[(size_t)cidx[w][k + 2] * NC];
    f16x2 v3 = *(const f16x2*)&Yc[(size_t)cidx[w][k + 3] * NC];
    f16x2 v4 = *(const f16x2*)&Yc[(size_t)cidx[w][k + 4] * NC];
    f16x2 v5 = *(const f16x2*)&Yc[(size_t)cidx[w][k + 5] * NC];
    f16x2 v6 = *(const f16x2*)&Yc[(size_t)cidx[w][k + 6] * NC];
    f16x2 v7 = *(const f16x2*)&Yc[(size_t)cidx[w][k + 7] * NC];
    a0 += (((float)v0[0] + (float)v1[0]) + ((float)v2[0] + (float)v3[0])) +
          (((float)v4[0] + (float)v5[0]) + ((float)v6[0] + (float)v7[0]));
    a1 += (((float)v0[1] + (float)v1[1]) + ((float)v2[1] + (float)v3[1])) +
          (((float)v4[1] + (float)v5[1]) + ((float)v6[1] + (float)v7[1]));
  }
  for (; k < n; ++k) {
    f16x2 v = *(const f16x2*)&Yc[(size_t)cidx[w][k] * NC];
    a0 += (float)v[0]; a1 += (float)v[1];
  }
  f16x2 vs = *(const f16x2*)&Yc[(size_t)row * NC];  // +I (eye)
  a0 += (float)vs[0]; a1 += (float)vs[1];
  const float di = dinv[row];
  float o0 = di * a0 + bias[cb];
  float o1 = di * a1 + bias[cb + 1];
  if (RELU) { o0 = fmaxf(o0, 0.f); o1 = fmaxf(o1, 0.f); }
  if constexpr (sizeof(OutT) == 4) {
    *(float2*)&out[(size_t)row * NC + cb] = make_float2(o0, o1);
  } else {
    f16x2 h = {(f16)o0, (f16)o1};
    *(f16x2*)&out[(size_t)row * NC + cb] = h;
  }
}

// ---------------------------------------------------------------------------
extern "C" void kernel_launch(void* const* d_in, const int* in_sizes, int n_in,
                              void* d_out, int out_size, void* d_ws, size_t ws_size,
                              hipStream_t stream) {
  const float* x  = (const float*)d_in[0];
  const int*   ei = (const int*)d_in[1];
  const float* W1 = (const float*)d_in[2];
  const float* b1 = (const float*)d_in[3];
  const float* W2 = (const float*)d_in[4];
  const float* b2 = (const float*)d_in[5];
  const float* W3 = (const float*)d_in[6];
  const float* b3 = (const float*)d_in[7];
  float* out = (float*)d_out;
  const int E = in_sizes[1] / 2;

  // Workspace (~19 MB). mask aliases Ys: mask dead after mask_to_csr, before
  // gemm1's first write to Ys.
  uint8_t* ws = (uint8_t*)d_ws;
  uint16_t* cols = (uint16_t*)ws;                                  // 3 MB
  int*      nnz  = (int*)(ws + (size_t)CSTRIDE * NN * 2);          // 32 KB
  float*    dinv = (float*)(ws + (size_t)CSTRIDE * NN * 2 + 32 * 1024);   // 32 KB
  f16*      H    = (f16*)(ws + (size_t)CSTRIDE * NN * 2 + 64 * 1024);     // 8 MB
  f16*      Ys   = H + (size_t)NN * 512;                           // 8 MB
  uint32_t* mask = (uint32_t*)Ys;                                  // 8 MB (alias)

  // ws is poisoned 0xAA before every call -> rebuild adjacency every launch
  hipMemsetAsync(mask, 0, (size_t)NN * WPR * sizeof(uint32_t), stream);
  build_adj<<<(E + 255) / 256, 256, 0, stream>>>(ei, mask, E);
  mask_to_csr<<<NN / 4, 256, 0, stream>>>(mask, cols, nnz, dinv);

  // Layer 1: Ys = f16(dinv ⊙ (x@W1)); H = relu(dinv ⊙ ((A+I)·Ys) + b1) in f16
  gemm_f16<float><<<dim3(8, 64), 256, 0, stream>>>(x, W1, dinv, Ys, NN, 512, 512);
  spmm_csr<512, f16, true><<<(NN / 4) * 4, 256, 0, stream>>>(cols, nnz, dinv, Ys, b1, H);

  // Layer 2
  gemm_f16<f16><<<dim3(8, 64), 256, 0, stream>>>(H, W2, dinv, Ys, NN, 512, 512);
  spmm_csr<512, f16, true><<<(NN / 4) * 4, 256, 0, stream>>>(cols, nnz, dinv, Ys, b2, H);

  // Layer 3 (no ReLU), fp32 -> d_out
  gemm_f16<f16><<<dim3(4, 64), 256, 0, stream>>>(H, W3, dinv, Ys, NN, 256, 512);
  spmm_csr<256, float, false><<<(NN / 4) * 2, 256, 0, stream>>>(cols, nnz, dinv, Ys, b3, out);
}

// Round 8
// 223.543 us; speedup vs baseline: 3.1135x; 1.0744x over previous
//
#include <hip/hip_runtime.h>
#include <stdint.h>

#define NN 8192       // nodes
#define WPR 256       // u32 words per bitmask row (8192 bits)
#define CSTRIDE 192   // CSR slots/row; P[deg>192] ~ 1e-40 for Poisson(64); writes guarded

typedef _Float16 f16;
typedef f16 f16x2 __attribute__((ext_vector_type(2)));
typedef f16 f16x4 __attribute__((ext_vector_type(4)));
typedef f16 f16x8 __attribute__((ext_vector_type(8)));
typedef float f32x4 __attribute__((ext_vector_type(4)));

// ---------------------------------------------------------------------------
// Adjacency bitmask: set semantics (duplicates collapse) via atomicOr
// ---------------------------------------------------------------------------
__global__ __launch_bounds__(256) void build_adj(const int* __restrict__ ei,
                                                 uint32_t* __restrict__ mask,
                                                 int E) {
  int t = blockIdx.x * blockDim.x + threadIdx.x;
  if (t >= E) return;
  int a = ei[t];        // e0
  int b = ei[E + t];    // e1
  atomicOr(&mask[(size_t)a * WPR + (b >> 5)], 1u << (b & 31));
  atomicOr(&mask[(size_t)b * WPR + (a >> 5)], 1u << (a & 31));
}

// ---------------------------------------------------------------------------
// Bitmask -> fixed-stride CSR (uint16 ids) + dinv. One wave per row. Self-edge
// bit stays (diag=2 case); eye handled separately in spmm. dinv=rsqrt(pop+1).
// ---------------------------------------------------------------------------
__global__ __launch_bounds__(256) void mask_to_csr(const uint32_t* __restrict__ mask,
                                                   uint16_t* __restrict__ cols,
                                                   int* __restrict__ nnz,
                                                   float* __restrict__ dinv) {
  const int row = blockIdx.x * 4 + (threadIdx.x >> 6);
  const int lane = threadIdx.x & 63;
  const uint4 w = ((const uint4*)(mask + (size_t)row * WPR))[lane];
  const int c = __popc(w.x) + __popc(w.y) + __popc(w.z) + __popc(w.w);
  int inc = c;
#pragma unroll
  for (int o = 1; o < 64; o <<= 1) {
    int v = __shfl_up(inc, o);
    if (lane >= o) inc += v;
  }
  const int total = __shfl(inc, 63);
  int base = row * CSTRIDE + (inc - c);
  const int lim = row * CSTRIDE + CSTRIDE;
  uint32_t ws_[4] = {w.x, w.y, w.z, w.w};
#pragma unroll
  for (int i = 0; i < 4; ++i) {
    uint32_t word = ws_[i];
    int boff = (lane * 4 + i) << 5;
    while (word) {
      int b = __ffs(word) - 1;
      word &= word - 1;
      if (base < lim) cols[base] = (uint16_t)(boff + b);
      ++base;
    }
  }
  if (lane == 0) {
    nnz[row] = (total > CSTRIDE) ? CSTRIDE : total;
    dinv[row] = rsqrtf((float)(total + 1));
  }
}

// ---------------------------------------------------------------------------
// One-shot weight prep: W fp32 [K=512][N] -> Wt f16 [N][K] (transposed),
// so GEMM B-staging is a pure f16x8 vector copy. Blocks 0..255 -> W1,
// 256..511 -> W2, 512..639 -> W3. 32x32 LDS tile transpose.
// ---------------------------------------------------------------------------
__global__ __launch_bounds__(256) void wcvt_all(const float* __restrict__ W1,
                                                const float* __restrict__ W2,
                                                const float* __restrict__ W3,
                                                f16* __restrict__ T1,
                                                f16* __restrict__ T2,
                                                f16* __restrict__ T3) {
  int tile = blockIdx.x;
  const float* W; f16* T; int N;
  if (tile < 256)      { W = W1; T = T1; N = 512; }
  else if (tile < 512) { W = W2; T = T2; N = 512; tile -= 256; }
  else                 { W = W3; T = T3; N = 256; tile -= 512; }
  const int K = 512;
  const int ntn = N >> 5;
  const int k0 = (tile / ntn) << 5, n0 = (tile % ntn) << 5;
  __shared__ f16 tl[32][33];
  const int tx = threadIdx.x & 31, ty = threadIdx.x >> 5;
#pragma unroll
  for (int r = 0; r < 32; r += 8)
    tl[ty + r][tx] = (f16)W[(size_t)(k0 + ty + r) * N + n0 + tx];
  __syncthreads();
#pragma unroll
  for (int r = 0; r < 32; r += 8)
    T[(size_t)(n0 + ty + r) * K + k0 + tx] = tl[tx][ty + r];
}

// ---------------------------------------------------------------------------
// f16-MFMA GEMM: Ys[m,:] = (f16)( rs[m] * (A@Wt^T)[m,:] )
// A [M,K] row-major (fp32 or f16); Wt f16 [N][K] (pre-transposed).
// BM=128, BN=64, BK=32; 256 thr = 2x2 waves; 16x16x32 f16 MFMA.
// A frag: row=lane&15, k=(lane>>4)*8+j. B frag: col=lane&15, same k.
// D frag: row=(lane>>4)*4+r, col=lane&15 (m89-verified, dtype-independent).
// ---------------------------------------------------------------------------
template <typename AT>
__global__ __launch_bounds__(256) void gemm_f16(const AT* __restrict__ A,
                                                const f16* __restrict__ Wt,
                                                const float* __restrict__ rs,
                                                f16* __restrict__ Ys,
                                                int M, int N, int K) {
  __shared__ f16 As[128][40];  // [m][k], pad -> benign 2-way conflicts
  __shared__ f16 Bs[64][40];   // [n][k]
  const int t = threadIdx.x;
  const int lane = t & 63;
  const int w = t >> 6;
  const int wr = w >> 1, wc = w & 1;          // 2x2 wave grid
  const int m0 = blockIdx.y * 128, n0 = blockIdx.x * 64;
  const int lm = lane & 15, kg = lane >> 4;   // fragment row/col, k-group
  const int k0f = kg * 8;

  f32x4 acc[4][2] = {};

  for (int k0 = 0; k0 < K; k0 += 32) {
    if constexpr (sizeof(AT) == 4) {
      // stage A: 128x32 fp32 -> f16. 4 float4 per thread.
#pragma unroll
      for (int l = 0; l < 4; ++l) {
        int row = (t >> 3) + l * 32;
        int c4 = (t & 7) * 4;
        float4 v = *(const float4*)&A[(size_t)(m0 + row) * K + k0 + c4];
        f16x4 h = {(f16)v.x, (f16)v.y, (f16)v.z, (f16)v.w};
        *(f16x4*)&As[row][c4] = h;
      }
    } else {
      // stage A: 128x32 f16 direct. 2 f16x8 per thread.
#pragma unroll
      for (int l = 0; l < 2; ++l) {
        int idx = l * 256 + t;
        int row = idx >> 2;
        int c8 = (idx & 3) * 8;
        f16x8 h = *(const f16x8*)&A[(size_t)(m0 + row) * K + k0 + c8];
        *(f16x8*)&As[row][c8] = h;
      }
    }
    // stage Wt: 64 n x 32 k f16, one f16x8 vector copy per thread.
    {
      int n = t >> 2, k8 = (t & 3) * 8;
      *(f16x8*)&Bs[n][k8] = *(const f16x8*)&Wt[(size_t)(n0 + n) * K + k0 + k8];
    }
    __syncthreads();

    f16x8 af[4], bf[2];
#pragma unroll
    for (int mf = 0; mf < 4; ++mf)
      af[mf] = *(const f16x8*)&As[wr * 64 + mf * 16 + lm][k0f];
#pragma unroll
    for (int nf = 0; nf < 2; ++nf)
      bf[nf] = *(const f16x8*)&Bs[wc * 32 + nf * 16 + lm][k0f];
#pragma unroll
    for (int mf = 0; mf < 4; ++mf)
#pragma unroll
      for (int nf = 0; nf < 2; ++nf)
        acc[mf][nf] = __builtin_amdgcn_mfma_f32_16x16x32_f16(af[mf], bf[nf], acc[mf][nf], 0, 0, 0);
    __syncthreads();
  }

  // epilogue: row-scale by rs, convert f16, store
#pragma unroll
  for (int mf = 0; mf < 4; ++mf) {
#pragma unroll
    for (int r = 0; r < 4; ++r) {
      int row = m0 + wr * 64 + mf * 16 + kg * 4 + r;
      float s = rs[row];
#pragma unroll
      for (int nf = 0; nf < 2; ++nf) {
        int col = n0 + wc * 32 + nf * 16 + lm;
        Ys[(size_t)row * N + col] = (f16)(s * acc[mf][nf][r]);
      }
    }
  }
}

// ---------------------------------------------------------------------------
// Column-chunked CSR SpMM with XCD affinity.
//   out[row, chunk] = dinv[row]*( sum_j Ys[j, chunk] + Ys[row, chunk] ) + bias
// chunk = blockIdx % Q (Q = NC/128): under round-robin block->XCD dispatch,
// each XCD touches ONE 2 MB column chunk of Ys -> L2-resident gathers.
// Block = 4 rows x 1 chunk; one wave per row; lane covers 2 cols.
// Inner: packed f16x2 tree-accumulation per 8 neighbors, fp32 flush.
// ---------------------------------------------------------------------------
template <int NC, typename OutT, bool RELU>
__global__ __launch_bounds__(256) void spmm_csr(const uint16_t* __restrict__ cols,
                                                const int* __restrict__ nnz,
                                                const float* __restrict__ dinv,
                                                const f16* __restrict__ Ys,
                                                const float* __restrict__ bias,
                                                OutT* __restrict__ out) {
  constexpr int Q = NC / 128;
  const int b = blockIdx.x;
  const int chunk = b % Q;          // == XCD%Q under round-robin dispatch
  const int rg = b / Q;
  const int w = threadIdx.x >> 6, lane = threadIdx.x & 63;
  const int row = rg * 4 + w;
  const int cb = chunk * 128 + 2 * lane;

  __shared__ uint16_t cidx[4][CSTRIDE];
  const int n = nnz[row];
  for (int k = lane; k < n; k += 64) cidx[w][k] = cols[row * CSTRIDE + k];
  __syncthreads();

  const f16* __restrict__ Yc = Ys + cb;
  float a0 = 0.f, a1 = 0.f;
  int k = 0;
  for (; k + 8 <= n; k += 8) {
    f16x2 v0 = *(const f16x2*)&Yc[(size_t)cidx[w][k + 0] * NC];
    f16x2 v1 = *(const f16x2*)&Yc[(size_t)cidx[w][k + 1] * NC];
    f16x2 v2 = *(const f16x2*)&Yc[(size_t)cidx[w][k + 2] * NC];
    f16x2 v3 = *(const f16x2*)&Yc[(size_t)cidx[w][k + 3] * NC];
    f16x2 v4 = *(const f16x2*)&Yc[(size_t)cidx[w][k + 4] * NC];
    f16x2 v5 = *(const f16x2*)&Yc[(size_t)cidx[w][k + 5] * NC];
    f16x2 v6 = *(const f16x2*)&Yc[(size_t)cidx[w][k + 6] * NC];
    f16x2 v7 = *(const f16x2*)&Yc[(size_t)cidx[w][k + 7] * NC];
    // packed tree-sum (7x v_pk_add_f16), single fp32 flush
    f16x2 s = ((v0 + v1) + (v2 + v3)) + ((v4 + v5) + (v6 + v7));
    a0 += (float)s[0];
    a1 += (float)s[1];
  }
  for (; k < n; ++k) {
    f16x2 v = *(const f16x2*)&Yc[(size_t)cidx[w][k] * NC];
    a0 += (float)v[0]; a1 += (float)v[1];
  }
  f16x2 vs = *(const f16x2*)&Yc[(size_t)row * NC];  // +I (eye)
  a0 += (float)vs[0]; a1 += (float)vs[1];
  const float di = dinv[row];
  float o0 = di * a0 + bias[cb];
  float o1 = di * a1 + bias[cb + 1];
  if (RELU) { o0 = fmaxf(o0, 0.f); o1 = fmaxf(o1, 0.f); }
  if constexpr (sizeof(OutT) == 4) {
    *(float2*)&out[(size_t)row * NC + cb] = make_float2(o0, o1);
  } else {
    f16x2 h = {(f16)o0, (f16)o1};
    *(f16x2*)&out[(size_t)row * NC + cb] = h;
  }
}

// ---------------------------------------------------------------------------
extern "C" void kernel_launch(void* const* d_in, const int* in_sizes, int n_in,
                              void* d_out, int out_size, void* d_ws, size_t ws_size,
                              hipStream_t stream) {
  const float* x  = (const float*)d_in[0];
  const int*   ei = (const int*)d_in[1];
  const float* W1 = (const float*)d_in[2];
  const float* b1 = (const float*)d_in[3];
  const float* W2 = (const float*)d_in[4];
  const float* b2 = (const float*)d_in[5];
  const float* W3 = (const float*)d_in[6];
  const float* b3 = (const float*)d_in[7];
  float* out = (float*)d_out;
  const int E = in_sizes[1] / 2;

  // Workspace (~21 MB). mask aliases Ys: mask dead after mask_to_csr, before
  // gemm1's first write to Ys.
  uint8_t* ws = (uint8_t*)d_ws;
  size_t off = 0;
  uint16_t* cols = (uint16_t*)ws;            off += (size_t)CSTRIDE * NN * 2;  // 3 MB
  int*      nnz  = (int*)(ws + off);         off += (size_t)NN * 4;            // 32 KB
  float*    dinv = (float*)(ws + off);       off += (size_t)NN * 4;            // 32 KB
  f16*      Wt1  = (f16*)(ws + off);         off += (size_t)512 * 512 * 2;     // 512 KB
  f16*      Wt2  = (f16*)(ws + off);         off += (size_t)512 * 512 * 2;     // 512 KB
  f16*      Wt3  = (f16*)(ws + off);         off += (size_t)256 * 512 * 2;     // 256 KB
  f16*      H    = (f16*)(ws + off);         off += (size_t)NN * 512 * 2;      // 8 MB
  f16*      Ys   = (f16*)(ws + off);                                           // 8 MB
  uint32_t* mask = (uint32_t*)Ys;                                              // alias

  // ws is poisoned 0xAA before every call -> rebuild adjacency every launch
  hipMemsetAsync(mask, 0, (size_t)NN * WPR * sizeof(uint32_t), stream);
  build_adj<<<(E + 255) / 256, 256, 0, stream>>>(ei, mask, E);
  mask_to_csr<<<NN / 4, 256, 0, stream>>>(mask, cols, nnz, dinv);
  wcvt_all<<<640, 256, 0, stream>>>(W1, W2, W3, Wt1, Wt2, Wt3);

  // Layer 1: Ys = f16(dinv ⊙ (x@W1)); H = relu(dinv ⊙ ((A+I)·Ys) + b1) in f16
  gemm_f16<float><<<dim3(8, 64), 256, 0, stream>>>(x, Wt1, dinv, Ys, NN, 512, 512);
  spmm_csr<512, f16, true><<<(NN / 4) * 4, 256, 0, stream>>>(cols, nnz, dinv, Ys, b1, H);

  // Layer 2
  gemm_f16<f16><<<dim3(8, 64), 256, 0, stream>>>(H, Wt2, dinv, Ys, NN, 512, 512);
  spmm_csr<512, f16, true><<<(NN / 4) * 4, 256, 0, stream>>>(cols, nnz, dinv, Ys, b2, H);

  // Layer 3 (no ReLU), fp32 -> d_out
  gemm_f16<f16><<<dim3(4, 64), 256, 0, stream>>>(H, Wt3, dinv, Ys, NN, 256, 512);
  spmm_csr<256, float, false><<<(NN / 4) * 2, 256, 0, stream>>>(cols, nnz, dinv, Ys, b3, out);
}